// Round 3
// baseline (457.540 us; speedup 1.0000x reference)
//
#include <hip/hip_runtime.h>
#include <math.h>

#define H_IMG 64
#define W_IMG 64
#define PIX   (H_IMG * W_IMG)   // 4096
#define NB    4
#define NHEADS 8
#define HD    32
#define CDIM  256
#define QKV_C 768
#define ATT_SCALE 0.17677669529663687f  // 32^-0.5

// ----------------------------------------------------------------------------
// QKV GEMM with bias, TRANSPOSED store: YT[b][p][o] = sum_c W[o][c] X[b][c][p].
// 128x128 tile, 256 threads, 8x8 per thread, KT=16.
// Transposed epilogue: per output pixel p, the 8 o-values are contiguous ->
// two float4 stores per (thread, ni).
// ----------------------------------------------------------------------------
__launch_bounds__(256)
__global__ void gemm_qkv_T(const float* __restrict__ W,
                           const float* __restrict__ bias,
                           const float* __restrict__ X,
                           float* __restrict__ YT,
                           int M, int K, int N) {
    __shared__ float As[16][128];   // As[k][m]
    __shared__ float Bs[16][128];   // Bs[k][n]

    const int b = blockIdx.z;
    const float* Xb = X + (size_t)b * K * N;
    float* YbT = YT + (size_t)b * N * M;

    const int m0 = blockIdx.y * 128;
    const int n0 = blockIdx.x * 128;
    const int t  = threadIdx.x;
    const int tx = t & 15;
    const int ty = t >> 4;
    const int m_base = ty * 8;
    const int n_base = tx * 8;

    float acc[8][8];
#pragma unroll
    for (int i = 0; i < 8; i++)
#pragma unroll
        for (int j = 0; j < 8; j++) acc[i][j] = 0.f;

    for (int c0 = 0; c0 < K; c0 += 16) {
#pragma unroll
        for (int i = 0; i < 2; i++) {
            int idx = t + i * 256;
            int mm = idx >> 2;
            int k4 = idx & 3;
            float4 v = *(const float4*)(W + (size_t)(m0 + mm) * K + c0 + k4 * 4);
            As[k4 * 4 + 0][mm] = v.x;
            As[k4 * 4 + 1][mm] = v.y;
            As[k4 * 4 + 2][mm] = v.z;
            As[k4 * 4 + 3][mm] = v.w;
        }
#pragma unroll
        for (int i = 0; i < 2; i++) {
            int idx = t + i * 256;
            int kk = idx >> 5;
            int n4 = idx & 31;
            float4 v = *(const float4*)(Xb + (size_t)(c0 + kk) * N + n0 + n4 * 4);
            *(float4*)&Bs[kk][n4 * 4] = v;
        }
        __syncthreads();

#pragma unroll
        for (int kk = 0; kk < 16; kk++) {
            float a[8], bb[8];
            *(float4*)&a[0]  = *(const float4*)&As[kk][m_base];
            *(float4*)&a[4]  = *(const float4*)&As[kk][m_base + 4];
            *(float4*)&bb[0] = *(const float4*)&Bs[kk][n_base];
            *(float4*)&bb[4] = *(const float4*)&Bs[kk][n_base + 4];
#pragma unroll
            for (int mi = 0; mi < 8; mi++)
#pragma unroll
                for (int ni = 0; ni < 8; ni++)
                    acc[mi][ni] += a[mi] * bb[ni];
        }
        __syncthreads();
    }

    float4 b0 = *(const float4*)(bias + m0 + m_base);
    float4 b1 = *(const float4*)(bias + m0 + m_base + 4);
#pragma unroll
    for (int ni = 0; ni < 8; ni++) {
        int p = n0 + n_base + ni;
        float* yp = YbT + (size_t)p * M + m0 + m_base;
        float4 v0, v1;
        v0.x = acc[0][ni] + b0.x; v0.y = acc[1][ni] + b0.y;
        v0.z = acc[2][ni] + b0.z; v0.w = acc[3][ni] + b0.w;
        v1.x = acc[4][ni] + b1.x; v1.y = acc[5][ni] + b1.y;
        v1.z = acc[6][ni] + b1.z; v1.w = acc[7][ni] + b1.w;
        *(float4*)yp = v0;
        *(float4*)(yp + 4) = v1;
    }
}

// ----------------------------------------------------------------------------
// Proj GEMM with bias, TRANSPOSED B input: Y[b][o][p] = sum_c W[o][c] XT[b][p][c]
// Standard (row-major [o][p]) output, since d_out is (B, C, H, W).
// ----------------------------------------------------------------------------
__launch_bounds__(256)
__global__ void gemm_proj_BT(const float* __restrict__ W,
                             const float* __restrict__ bias,
                             const float* __restrict__ XT,
                             float* __restrict__ Y,
                             int M, int K, int N) {
    __shared__ float As[16][128];   // As[k][m]
    __shared__ float Bs[16][128];   // Bs[k][n]

    const int b = blockIdx.z;
    const float* XTb = XT + (size_t)b * N * K;
    float* Yb = Y + (size_t)b * M * N;

    const int m0 = blockIdx.y * 128;
    const int n0 = blockIdx.x * 128;
    const int t  = threadIdx.x;
    const int tx = t & 15;
    const int ty = t >> 4;
    const int m_base = ty * 8;
    const int n_base = tx * 8;

    float acc[8][8];
#pragma unroll
    for (int i = 0; i < 8; i++)
#pragma unroll
        for (int j = 0; j < 8; j++) acc[i][j] = 0.f;

    for (int c0 = 0; c0 < K; c0 += 16) {
#pragma unroll
        for (int i = 0; i < 2; i++) {
            int idx = t + i * 256;
            int mm = idx >> 2;
            int k4 = idx & 3;
            float4 v = *(const float4*)(W + (size_t)(m0 + mm) * K + c0 + k4 * 4);
            As[k4 * 4 + 0][mm] = v.x;
            As[k4 * 4 + 1][mm] = v.y;
            As[k4 * 4 + 2][mm] = v.z;
            As[k4 * 4 + 3][mm] = v.w;
        }
        // B tile from transposed activation: XT[p][c]
#pragma unroll
        for (int i = 0; i < 2; i++) {
            int idx = t + i * 256;
            int nn = idx >> 2;               // 0..127 pixel within tile
            int k4 = idx & 3;
            float4 v = *(const float4*)(XTb + (size_t)(n0 + nn) * K + c0 + k4 * 4);
            Bs[k4 * 4 + 0][nn] = v.x;
            Bs[k4 * 4 + 1][nn] = v.y;
            Bs[k4 * 4 + 2][nn] = v.z;
            Bs[k4 * 4 + 3][nn] = v.w;
        }
        __syncthreads();

#pragma unroll
        for (int kk = 0; kk < 16; kk++) {
            float a[8], bb[8];
            *(float4*)&a[0]  = *(const float4*)&As[kk][m_base];
            *(float4*)&a[4]  = *(const float4*)&As[kk][m_base + 4];
            *(float4*)&bb[0] = *(const float4*)&Bs[kk][n_base];
            *(float4*)&bb[4] = *(const float4*)&Bs[kk][n_base + 4];
#pragma unroll
            for (int mi = 0; mi < 8; mi++)
#pragma unroll
                for (int ni = 0; ni < 8; ni++)
                    acc[mi][ni] += a[mi] * bb[ni];
        }
        __syncthreads();
    }

#pragma unroll
    for (int mi = 0; mi < 8; mi++) {
        int row = m0 + m_base + mi;
        float bs = bias[row];
        float* yp = Yb + (size_t)row * N + n0 + n_base;
#pragma unroll
        for (int j4 = 0; j4 < 2; j4++) {
            float4 v;
            v.x = acc[mi][j4 * 4 + 0] + bs;
            v.y = acc[mi][j4 * 4 + 1] + bs;
            v.z = acc[mi][j4 * 4 + 2] + bs;
            v.w = acc[mi][j4 * 4 + 3] + bs;
            *(float4*)(yp + j4 * 4) = v;
        }
    }
}

// ----------------------------------------------------------------------------
// Fused local neighborhood attention on pixel-major qkvT[b][p][o].
// One pixel's k (or v) head-vector = 32 contiguous floats = one 128B cache
// line -> 8 dwordx4 loads per neighbor instead of 32 strided scalar loads.
// Zero-padding semantics: OOB neighbors contribute logit=rpb[l] to the
// softmax denominator with zero value. Max-free exp-sum softmax (logits
// are O(0.1), safe in fp32).
// ----------------------------------------------------------------------------
template <int KS, int DIL>
__device__ __forceinline__ void attn_pxT(const float* __restrict__ qkvT,
                                         const float* __restrict__ rp,
                                         float* __restrict__ outT,
                                         int b, int h, int px, int py) {
    const int p = py * W_IMG + px;
    const float* base = qkvT + (size_t)b * PIX * QKV_C;
    const float4* qp = (const float4*)(base + (size_t)p * QKV_C + h * HD);

    float4 q[8];
#pragma unroll
    for (int r = 0; r < 8; r++) {
        float4 tq = qp[r];
        tq.x *= ATT_SCALE; tq.y *= ATT_SCALE; tq.z *= ATT_SCALE; tq.w *= ATT_SCALE;
        q[r] = tq;
    }
    float4 acc[8];
#pragma unroll
    for (int r = 0; r < 8; r++) acc[r] = make_float4(0.f, 0.f, 0.f, 0.f);
    float denom = 0.f;
    const int ko = CDIM + h * HD;
    const int vo = 2 * CDIM + h * HD;

#pragma unroll 1
    for (int i = 0; i < KS; i++) {
        const int yy = py + (i - KS / 2) * DIL;
        const float* rrow = rp + i * KS;
        if ((unsigned)yy < (unsigned)H_IMG) {
#pragma unroll
            for (int j = 0; j < KS; j++) {
                const int xx = px + (j - KS / 2) * DIL;
                const float rb = rrow[j];
                if ((unsigned)xx < (unsigned)W_IMG) {
                    const float* nb = base + (size_t)(yy * W_IMG + xx) * QKV_C;
                    const float4* kv = (const float4*)(nb + ko);
                    float4 s4 = make_float4(0.f, 0.f, 0.f, 0.f);
#pragma unroll
                    for (int r = 0; r < 8; r++) {
                        float4 kk = kv[r];
                        s4.x += q[r].x * kk.x; s4.y += q[r].y * kk.y;
                        s4.z += q[r].z * kk.z; s4.w += q[r].w * kk.w;
                    }
                    const float w = __expf(rb + (s4.x + s4.y) + (s4.z + s4.w));
                    denom += w;
                    const float4* vv = (const float4*)(nb + vo);
#pragma unroll
                    for (int r = 0; r < 8; r++) {
                        float4 vl = vv[r];
                        acc[r].x += w * vl.x; acc[r].y += w * vl.y;
                        acc[r].z += w * vl.z; acc[r].w += w * vl.w;
                    }
                } else {
                    denom += __expf(rb);   // zero-padded neighbor
                }
            }
        } else {
#pragma unroll
            for (int j = 0; j < KS; j++) denom += __expf(rrow[j]);
        }
    }

    const float inv = 1.f / denom;
    float4* op = (float4*)(outT + (size_t)b * PIX * CDIM + (size_t)p * CDIM + h * HD);
#pragma unroll
    for (int r = 0; r < 8; r++) {
        float4 tv = acc[r];
        tv.x *= inv; tv.y *= inv; tv.z *= inv; tv.w *= inv;
        op[r] = tv;
    }
}

__launch_bounds__(256)
__global__ void attn_fused_T(const float* __restrict__ qkvT,
                             const float* __restrict__ rpb0,
                             const float* __restrict__ rpb1,
                             const float* __restrict__ rpb2,
                             float* __restrict__ outT) {
    const int bh = blockIdx.x;
    const int b  = bh >> 3;
    const int h  = bh & 7;
    const int px = threadIdx.x;                       // 0..63
    const int py = blockIdx.y * 4 + threadIdx.y;      // 0..63

    if (h < 4) {
        attn_pxT<5, 1>(qkvT, rpb0 + h * 25, outT, b, h, px, py);
    } else if (h < 7) {
        attn_pxT<7, 2>(qkvT, rpb1 + (h - 4) * 49, outT, b, h, px, py);
    } else {
        attn_pxT<9, 3>(qkvT, rpb2, outT, b, h, px, py);
    }
}

// ----------------------------------------------------------------------------
extern "C" void kernel_launch(void* const* d_in, const int* in_sizes, int n_in,
                              void* d_out, int out_size, void* d_ws, size_t ws_size,
                              hipStream_t stream) {
    const float* x      = (const float*)d_in[0];
    const float* qkv_w  = (const float*)d_in[1];
    const float* qkv_b  = (const float*)d_in[2];
    const float* proj_w = (const float*)d_in[3];
    const float* proj_b = (const float*)d_in[4];
    const float* rpb0   = (const float*)d_in[5];
    const float* rpb1   = (const float*)d_in[6];
    const float* rpb2   = (const float*)d_in[7];
    float* out = (float*)d_out;

    // workspace: qkvT (4*4096*768 fp32 = 48 MB) | attT (4*4096*256 fp32 = 16 MB)
    float* qkvT = (float*)d_ws;
    float* attT = qkvT + (size_t)NB * PIX * QKV_C;

    dim3 gblk(256);
    // QKV projection (transposed store): M=768, K=256, N=4096 per batch
    gemm_qkv_T<<<dim3(PIX / 128, QKV_C / 128, NB), gblk, 0, stream>>>(
        qkv_w, qkv_b, x, qkvT, QKV_C, CDIM, PIX);

    // Fused multi-range attention on pixel-major layout
    attn_fused_T<<<dim3(NB * NHEADS, 16), dim3(64, 4), 0, stream>>>(
        qkvT, rpb0, rpb1, rpb2, attT);

    // Output projection (transposed B input): M=256, K=256, N=4096 per batch
    gemm_proj_BT<<<dim3(PIX / 128, CDIM / 128, NB), gblk, 0, stream>>>(
        proj_w, proj_b, attT, out, CDIM, CDIM, PIX);
}

// Round 4
// 297.337 us; speedup vs baseline: 1.5388x; 1.5388x over previous
//
#include <hip/hip_runtime.h>
#include <math.h>

#define H_IMG 64
#define W_IMG 64
#define PIX   (H_IMG * W_IMG)   // 4096
#define NB    4
#define NHEADS 8
#define HD    32
#define CDIM  256
#define QKV_C 768
#define ATT_SCALE 0.17677669529663687f  // 32^-0.5

// ----------------------------------------------------------------------------
// fp32 GEMM with bias: Y[b] = W (MxK) @ X[b] (KxN) + bias  (standard layout)
// 128x128 tile, 256 threads, 8x8 per thread, KT=16.
// ----------------------------------------------------------------------------
__launch_bounds__(256)
__global__ void gemm_bias_f32(const float* __restrict__ W,
                              const float* __restrict__ bias,
                              const float* __restrict__ X,
                              float* __restrict__ Y,
                              int M, int K, int N) {
    __shared__ float As[16][128];   // As[k][m]
    __shared__ float Bs[16][128];   // Bs[k][n]

    const int b = blockIdx.z;
    const float* Xb = X + (size_t)b * K * N;
    float* Yb = Y + (size_t)b * M * N;

    const int m0 = blockIdx.y * 128;
    const int n0 = blockIdx.x * 128;
    const int t  = threadIdx.x;
    const int tx = t & 15;
    const int ty = t >> 4;
    const int m_base = ty * 8;
    const int n_base = tx * 8;

    float acc[8][8];
#pragma unroll
    for (int i = 0; i < 8; i++)
#pragma unroll
        for (int j = 0; j < 8; j++) acc[i][j] = 0.f;

    for (int c0 = 0; c0 < K; c0 += 16) {
#pragma unroll
        for (int i = 0; i < 2; i++) {
            int idx = t + i * 256;
            int mm = idx >> 2;
            int k4 = idx & 3;
            float4 v = *(const float4*)(W + (size_t)(m0 + mm) * K + c0 + k4 * 4);
            As[k4 * 4 + 0][mm] = v.x;
            As[k4 * 4 + 1][mm] = v.y;
            As[k4 * 4 + 2][mm] = v.z;
            As[k4 * 4 + 3][mm] = v.w;
        }
#pragma unroll
        for (int i = 0; i < 2; i++) {
            int idx = t + i * 256;
            int kk = idx >> 5;
            int n4 = idx & 31;
            float4 v = *(const float4*)(Xb + (size_t)(c0 + kk) * N + n0 + n4 * 4);
            *(float4*)&Bs[kk][n4 * 4] = v;
        }
        __syncthreads();

#pragma unroll
        for (int kk = 0; kk < 16; kk++) {
            float a[8], bb[8];
            *(float4*)&a[0]  = *(const float4*)&As[kk][m_base];
            *(float4*)&a[4]  = *(const float4*)&As[kk][m_base + 4];
            *(float4*)&bb[0] = *(const float4*)&Bs[kk][n_base];
            *(float4*)&bb[4] = *(const float4*)&Bs[kk][n_base + 4];
#pragma unroll
            for (int mi = 0; mi < 8; mi++)
#pragma unroll
                for (int ni = 0; ni < 8; ni++)
                    acc[mi][ni] += a[mi] * bb[ni];
        }
        __syncthreads();
    }

#pragma unroll
    for (int mi = 0; mi < 8; mi++) {
        int row = m0 + m_base + mi;
        float bs = bias[row];
        float* yp = Yb + (size_t)row * N + n0 + n_base;
#pragma unroll
        for (int j4 = 0; j4 < 2; j4++) {
            float4 v;
            v.x = acc[mi][j4 * 4 + 0] + bs;
            v.y = acc[mi][j4 * 4 + 1] + bs;
            v.z = acc[mi][j4 * 4 + 2] + bs;
            v.w = acc[mi][j4 * 4 + 3] + bs;
            *(float4*)(yp + j4 * 4) = v;
        }
    }
}

// ----------------------------------------------------------------------------
// Shfl-based local neighborhood attention, channel-major layout.
// One wave (64 lanes) = one image row of one (b, head). Lane = x.
// Per key-row i: load k-row and v-row ONCE (coalesced, 64 loads), serve all
// KS x-offsets via __shfl (ds_bpermute lane crossbar, no LDS storage).
// Zero-padding semantics: OOB neighbors contribute exp(rpb) to denom, v=0.
// Max-free exp-sum softmax (logits O(0.1), safe in fp32).
// ----------------------------------------------------------------------------
template <int KS, int DIL>
__device__ __forceinline__ void attn_row(const float* __restrict__ qkv,
                                         const float* __restrict__ rp,
                                         float* __restrict__ out,
                                         int b, int h, int y) {
    const int x = threadIdx.x;   // 0..63, lane = x coordinate

    const float* qbase = qkv + ((size_t)b * QKV_C + h * HD) * PIX + y * W_IMG;
    const float* kbase = qkv + ((size_t)b * QKV_C + CDIM + h * HD) * PIX;
    const float* vbase = qkv + ((size_t)b * QKV_C + 2 * CDIM + h * HD) * PIX;

    float q[HD];
#pragma unroll
    for (int d = 0; d < HD; d++) q[d] = qbase[(size_t)d * PIX + x] * ATT_SCALE;

    float acc[HD];
#pragma unroll
    for (int d = 0; d < HD; d++) acc[d] = 0.f;
    float denom = 0.f;

#pragma unroll 1
    for (int i = 0; i < KS; i++) {
        const int yy = y + (i - KS / 2) * DIL;
        const float* rrow = rp + i * KS;
        if ((unsigned)yy < (unsigned)H_IMG) {
            // Load this key-row and value-row once, coalesced.
            float kr[HD], vr[HD];
            const float* krow = kbase + yy * W_IMG;
            const float* vrow = vbase + yy * W_IMG;
#pragma unroll
            for (int d = 0; d < HD; d++) {
                kr[d] = krow[(size_t)d * PIX + x];
                vr[d] = vrow[(size_t)d * PIX + x];
            }
#pragma unroll
            for (int j = 0; j < KS; j++) {
                const int xx = x + (j - KS / 2) * DIL;
                const int src = xx & 63;
                const bool valid = (unsigned)xx < (unsigned)W_IMG;
                // dot(q, k[xx]) via lane crossbar; 4 partial chains for ILP
                float s0 = 0.f, s1 = 0.f, s2 = 0.f, s3 = 0.f;
#pragma unroll
                for (int d = 0; d < HD; d += 4) {
                    s0 += q[d + 0] * __shfl(kr[d + 0], src);
                    s1 += q[d + 1] * __shfl(kr[d + 1], src);
                    s2 += q[d + 2] * __shfl(kr[d + 2], src);
                    s3 += q[d + 3] * __shfl(kr[d + 3], src);
                }
                const float rb = rrow[j];
                const float logit = valid ? ((s0 + s1) + (s2 + s3) + rb) : rb;
                const float w = __expf(logit);
                denom += w;
                const float wv = valid ? w : 0.f;
#pragma unroll
                for (int d = 0; d < HD; d++)
                    acc[d] += wv * __shfl(vr[d], src);
            }
        } else {
            // whole key-row OOB: denominator-only contributions (wave-uniform)
#pragma unroll
            for (int j = 0; j < KS; j++) denom += __expf(rrow[j]);
        }
    }

    const float inv = 1.f / denom;
    float* op = out + ((size_t)b * CDIM + h * HD) * PIX + y * W_IMG;
#pragma unroll
    for (int d = 0; d < HD; d++) op[(size_t)d * PIX + x] = acc[d] * inv;
}

__launch_bounds__(64)
__global__ void attn_shfl(const float* __restrict__ qkv,
                          const float* __restrict__ rpb0,
                          const float* __restrict__ rpb1,
                          const float* __restrict__ rpb2,
                          float* __restrict__ out) {
    const int bh = blockIdx.x;     // consecutive blocks = different heads (balance)
    const int b  = bh >> 3;
    const int h  = bh & 7;
    const int y  = blockIdx.y;

    if (h < 4) {
        attn_row<5, 1>(qkv, rpb0 + h * 25, out, b, h, y);
    } else if (h < 7) {
        attn_row<7, 2>(qkv, rpb1 + (h - 4) * 49, out, b, h, y);
    } else {
        attn_row<9, 3>(qkv, rpb2, out, b, h, y);
    }
}

// ----------------------------------------------------------------------------
extern "C" void kernel_launch(void* const* d_in, const int* in_sizes, int n_in,
                              void* d_out, int out_size, void* d_ws, size_t ws_size,
                              hipStream_t stream) {
    const float* x      = (const float*)d_in[0];
    const float* qkv_w  = (const float*)d_in[1];
    const float* qkv_b  = (const float*)d_in[2];
    const float* proj_w = (const float*)d_in[3];
    const float* proj_b = (const float*)d_in[4];
    const float* rpb0   = (const float*)d_in[5];
    const float* rpb1   = (const float*)d_in[6];
    const float* rpb2   = (const float*)d_in[7];
    float* out = (float*)d_out;

    // workspace: qkv (4*768*4096 fp32 = 48 MB) | att (4*256*4096 fp32 = 16 MB)
    float* qkv = (float*)d_ws;
    float* att = qkv + (size_t)NB * QKV_C * PIX;

    dim3 gblk(256);
    // QKV projection: M=768, K=256, N=4096, per batch (channel-major out)
    gemm_bias_f32<<<dim3(PIX / 128, QKV_C / 128, NB), gblk, 0, stream>>>(
        qkv_w, qkv_b, x, qkv, QKV_C, CDIM, PIX);

    // Shfl attention: one wave per (b, h, row); 2048 one-wave blocks
    attn_shfl<<<dim3(NB * NHEADS, H_IMG), dim3(64), 0, stream>>>(
        qkv, rpb0, rpb1, rpb2, att);

    // Output projection: M=256, K=256, N=4096, per batch
    gemm_bias_f32<<<dim3(PIX / 128, CDIM / 128, NB), gblk, 0, stream>>>(
        proj_w, proj_b, att, out, CDIM, CDIM, PIX);
}

// Round 5
// 234.869 us; speedup vs baseline: 1.9481x; 1.2660x over previous
//
#include <hip/hip_runtime.h>
#include <math.h>

#define H_IMG 64
#define W_IMG 64
#define PIX   (H_IMG * W_IMG)   // 4096
#define NB    4
#define NHEADS 8
#define HD    32
#define CDIM  256
#define QKV_C 768
#define ATT_SCALE 0.17677669529663687f  // 32^-0.5

typedef _Float16 half8_t __attribute__((ext_vector_type(8)));
typedef float f32x4 __attribute__((ext_vector_type(4)));

// ----------------------------------------------------------------------------
// fp32 -> fp16 convert (weights)
// ----------------------------------------------------------------------------
__global__ void cvt_f16(const float* __restrict__ src, _Float16* __restrict__ dst, int n) {
    int i = blockIdx.x * 256 + threadIdx.x;
    if (i < n) dst[i] = (_Float16)src[i];
}

// ----------------------------------------------------------------------------
// Transpose + convert: src fp32 [b][C][PIX] -> dst fp16 [b][PIX][C].  C=256.
// 64x64 tiles via LDS; coalesced on both sides.
// ----------------------------------------------------------------------------
__launch_bounds__(256)
__global__ void transpose_to_f16(const float* __restrict__ src,
                                 _Float16* __restrict__ dst, int C) {
    __shared__ _Float16 tl[64][66];   // stride 66 halves = 33 dwords: conflict-free
    const int b  = blockIdx.z;
    const int p0 = blockIdx.x * 64;
    const int c0 = blockIdx.y * 64;
    const int tx = threadIdx.x;       // 0..63
    const int ty = threadIdx.y;       // 0..3
    const float* s = src + (size_t)b * C * PIX;
    _Float16* d = dst + (size_t)b * PIX * C;
#pragma unroll
    for (int cc = ty; cc < 64; cc += 4)
        tl[cc][tx] = (_Float16)s[(size_t)(c0 + cc) * PIX + p0 + tx];
    __syncthreads();
#pragma unroll
    for (int pp = ty; pp < 64; pp += 4)
        d[(size_t)(p0 + pp) * C + c0 + tx] = tl[tx][pp];
}

// ----------------------------------------------------------------------------
// fp16 MFMA GEMM: Y[b][m][n] = sum_k A[m][k] * BT[b][n][k] + bias[m]
// Both operands k-contiguous. 128x128 tile, BK=32, 4 waves (2x2), each wave
// 64x64 via 4x4 grid of 16x16x32 MFMA. LDS row stride 40 halves -> b128 frag
// reads tile all 32 banks (windows of 4 dwords at stride 20).
// Fragment mappings (m89/m120-verified): A[m=lane&15][k=(lane>>4)*8+j],
// B[k=(lane>>4)*8+j][n=lane&15], D[row=(lane>>4)*4+r][col=lane&15].
// ----------------------------------------------------------------------------
template <typename OutT>
__launch_bounds__(256)
__global__ void gemm16(const _Float16* __restrict__ A,
                       const _Float16* __restrict__ BT,
                       const float* __restrict__ bias,
                       OutT* __restrict__ Y,
                       int M, int K, int N) {
    __shared__ _Float16 Asl[128][40];
    __shared__ _Float16 Bsl[128][40];
    const int b = blockIdx.z;
    const _Float16* Bb = BT + (size_t)b * N * K;
    OutT* Yb = Y + (size_t)b * M * N;
    const int m0 = blockIdx.y * 128;
    const int n0 = blockIdx.x * 128;
    const int t    = threadIdx.x;
    const int lane = t & 63;
    const int w    = t >> 6;
    const int wm = w >> 1, wn = w & 1;
    const int l15 = lane & 15;
    const int kq  = (lane >> 4) * 8;

    f32x4 acc[4][4];
#pragma unroll
    for (int mt = 0; mt < 4; mt++)
#pragma unroll
        for (int nt = 0; nt < 4; nt++)
            acc[mt][nt] = (f32x4){0.f, 0.f, 0.f, 0.f};

    for (int k0 = 0; k0 < K; k0 += 32) {
        __syncthreads();
#pragma unroll
        for (int i = 0; i < 2; i++) {
            int idx = t + i * 256;
            int row = idx >> 2;
            int seg = (idx & 3) * 8;
            *(half8_t*)&Asl[row][seg] = *(const half8_t*)(A  + (size_t)(m0 + row) * K + k0 + seg);
            *(half8_t*)&Bsl[row][seg] = *(const half8_t*)(Bb + (size_t)(n0 + row) * K + k0 + seg);
        }
        __syncthreads();
        half8_t af[4], bf[4];
#pragma unroll
        for (int mt = 0; mt < 4; mt++)
            af[mt] = *(const half8_t*)&Asl[wm * 64 + mt * 16 + l15][kq];
#pragma unroll
        for (int nt = 0; nt < 4; nt++)
            bf[nt] = *(const half8_t*)&Bsl[wn * 64 + nt * 16 + l15][kq];
#pragma unroll
        for (int mt = 0; mt < 4; mt++)
#pragma unroll
            for (int nt = 0; nt < 4; nt++)
                acc[mt][nt] = __builtin_amdgcn_mfma_f32_16x16x32_f16(
                    af[mt], bf[nt], acc[mt][nt], 0, 0, 0);
    }

    const int rq = lane >> 4;
#pragma unroll
    for (int mt = 0; mt < 4; mt++) {
#pragma unroll
        for (int r = 0; r < 4; r++) {
            int m = m0 + wm * 64 + mt * 16 + rq * 4 + r;
            float bs = bias[m];
            OutT* yp = Yb + (size_t)m * N + n0 + wn * 64;
#pragma unroll
            for (int nt = 0; nt < 4; nt++)
                yp[nt * 16 + l15] = (OutT)(acc[mt][nt][r] + bs);
        }
    }
}

// ----------------------------------------------------------------------------
// Shfl attention with 2-wave i-split. qkv is fp16 channel-major [b][o][p].
// Wave wv handles key-rows i = wv, wv+2, ...; partial (denom, acc[32]) merged
// through LDS. Zero-padding semantics preserved (OOB: exp(rpb) into denom).
// ----------------------------------------------------------------------------
template <int KS, int DIL>
__device__ __forceinline__ void attn_row_split(const _Float16* __restrict__ qkv,
                                               const float* __restrict__ rp,
                                               float* __restrict__ out,
                                               int b, int h, int y, int wv,
                                               float (*lds)[HD + 1][64]) {
    const int x = threadIdx.x;   // 0..63, lane = x coordinate

    const _Float16* qbase = qkv + ((size_t)b * QKV_C + h * HD) * PIX + y * W_IMG;
    const _Float16* kbase = qkv + ((size_t)b * QKV_C + CDIM + h * HD) * PIX;
    const _Float16* vbase = qkv + ((size_t)b * QKV_C + 2 * CDIM + h * HD) * PIX;

    float q[HD];
#pragma unroll
    for (int d = 0; d < HD; d++) q[d] = (float)qbase[(size_t)d * PIX + x] * ATT_SCALE;

    float acc[HD];
#pragma unroll
    for (int d = 0; d < HD; d++) acc[d] = 0.f;
    float denom = 0.f;

#pragma unroll 1
    for (int i = wv; i < KS; i += 2) {
        const int yy = y + (i - KS / 2) * DIL;
        const float* rrow = rp + i * KS;
        if ((unsigned)yy < (unsigned)H_IMG) {
            float kr[HD], vr[HD];
            const _Float16* krow = kbase + yy * W_IMG;
            const _Float16* vrow = vbase + yy * W_IMG;
#pragma unroll
            for (int d = 0; d < HD; d++) {
                kr[d] = (float)krow[(size_t)d * PIX + x];
                vr[d] = (float)vrow[(size_t)d * PIX + x];
            }
#pragma unroll
            for (int j = 0; j < KS; j++) {
                const int xx = x + (j - KS / 2) * DIL;
                const int src = xx & 63;
                const bool valid = (unsigned)xx < (unsigned)W_IMG;
                float s0 = 0.f, s1 = 0.f, s2 = 0.f, s3 = 0.f;
#pragma unroll
                for (int d = 0; d < HD; d += 4) {
                    s0 += q[d + 0] * __shfl(kr[d + 0], src);
                    s1 += q[d + 1] * __shfl(kr[d + 1], src);
                    s2 += q[d + 2] * __shfl(kr[d + 2], src);
                    s3 += q[d + 3] * __shfl(kr[d + 3], src);
                }
                const float rb = rrow[j];
                const float logit = valid ? ((s0 + s1) + (s2 + s3) + rb) : rb;
                const float wgt = __expf(logit);
                denom += wgt;
                const float wv2 = valid ? wgt : 0.f;
#pragma unroll
                for (int d = 0; d < HD; d++)
                    acc[d] += wv2 * __shfl(vr[d], src);
            }
        } else {
#pragma unroll
            for (int j = 0; j < KS; j++) denom += __expf(rrow[j]);
        }
    }

    // Merge the two waves' partials through LDS
#pragma unroll
    for (int d = 0; d < HD; d++) lds[wv][d][x] = acc[d];
    lds[wv][HD][x] = denom;
    __syncthreads();

    const float inv = 1.f / (lds[0][HD][x] + lds[1][HD][x]);
    float* op = out + ((size_t)b * CDIM + h * HD) * PIX + y * W_IMG;
#pragma unroll
    for (int dd = 0; dd < HD / 2; dd++) {
        const int d = wv * (HD / 2) + dd;
        op[(size_t)d * PIX + x] = (lds[0][d][x] + lds[1][d][x]) * inv;
    }
}

__launch_bounds__(128)
__global__ void attn_shfl2(const _Float16* __restrict__ qkv,
                           const float* __restrict__ rpb0,
                           const float* __restrict__ rpb1,
                           const float* __restrict__ rpb2,
                           float* __restrict__ out) {
    __shared__ float lds[2][HD + 1][64];
    const int bh = blockIdx.x;
    const int b  = bh >> 3;
    const int h  = bh & 7;
    const int y  = blockIdx.y;
    const int wv = threadIdx.y;

    if (h < 4) {
        attn_row_split<5, 1>(qkv, rpb0 + h * 25, out, b, h, y, wv, lds);
    } else if (h < 7) {
        attn_row_split<7, 2>(qkv, rpb1 + (h - 4) * 49, out, b, h, y, wv, lds);
    } else {
        attn_row_split<9, 3>(qkv, rpb2, out, b, h, y, wv, lds);
    }
}

// ----------------------------------------------------------------------------
extern "C" void kernel_launch(void* const* d_in, const int* in_sizes, int n_in,
                              void* d_out, int out_size, void* d_ws, size_t ws_size,
                              hipStream_t stream) {
    const float* x      = (const float*)d_in[0];
    const float* qkv_w  = (const float*)d_in[1];
    const float* qkv_b  = (const float*)d_in[2];
    const float* proj_w = (const float*)d_in[3];
    const float* proj_b = (const float*)d_in[4];
    const float* rpb0   = (const float*)d_in[5];
    const float* rpb1   = (const float*)d_in[6];
    const float* rpb2   = (const float*)d_in[7];
    float* out = (float*)d_out;

    // Workspace layout (bytes):
    //   qkv16  [b][768][4096] fp16 : 24 MB
    //   att32  [b][256][4096] fp32 : 16 MB
    //   T16    [b][4096][256] fp16 :  8 MB  (xT16, then reused as attT16)
    //   W16    768x256 fp16, P16 256x256 fp16 : 0.5 MB
    char* ws = (char*)d_ws;
    _Float16* qkv16 = (_Float16*)ws;
    float*    att32 = (float*)(ws + (size_t)NB * QKV_C * PIX * 2);
    _Float16* T16   = (_Float16*)(ws + (size_t)NB * QKV_C * PIX * 2 + (size_t)NB * CDIM * PIX * 4);
    _Float16* W16   = T16 + (size_t)NB * PIX * CDIM;
    _Float16* P16   = W16 + (size_t)QKV_C * CDIM;

    // Convert weights to fp16
    cvt_f16<<<dim3((QKV_C * CDIM + 255) / 256), dim3(256), 0, stream>>>(qkv_w, W16, QKV_C * CDIM);
    cvt_f16<<<dim3((CDIM * CDIM + 255) / 256), dim3(256), 0, stream>>>(proj_w, P16, CDIM * CDIM);

    // Transpose+convert x: [b][256][4096] f32 -> [b][4096][256] f16
    transpose_to_f16<<<dim3(PIX / 64, CDIM / 64, NB), dim3(64, 4), 0, stream>>>(x, T16, CDIM);

    // QKV GEMM (fp16 MFMA, fp16 out): M=768, K=256, N=4096 per batch
    gemm16<_Float16><<<dim3(PIX / 128, QKV_C / 128, NB), dim3(256), 0, stream>>>(
        W16, T16, qkv_b, qkv16, QKV_C, CDIM, PIX);

    // Fused multi-range shfl attention, 2-wave i-split
    attn_shfl2<<<dim3(NB * NHEADS, H_IMG), dim3(64, 2), 0, stream>>>(
        qkv16, rpb0, rpb1, rpb2, att32);

    // Transpose+convert att: [b][256][4096] f32 -> [b][4096][256] f16
    transpose_to_f16<<<dim3(PIX / 64, CDIM / 64, NB), dim3(64, 4), 0, stream>>>(att32, T16, CDIM);

    // Proj GEMM (fp16 MFMA, fp32 out): M=256, K=256, N=4096 per batch
    gemm16<float><<<dim3(PIX / 128, CDIM / 128, NB), dim3(256), 0, stream>>>(
        P16, T16, proj_b, out, CDIM, CDIM, PIX);
}

// Round 6
// 171.275 us; speedup vs baseline: 2.6714x; 1.3713x over previous
//
#include <hip/hip_runtime.h>
#include <math.h>

#define H_IMG 64
#define W_IMG 64
#define PIX   (H_IMG * W_IMG)   // 4096
#define NB    4
#define NHEADS 8
#define HD    32
#define CDIM  256
#define QKV_C 768
#define ATT_SCALE 0.17677669529663687f  // 32^-0.5

typedef _Float16 half8_t __attribute__((ext_vector_type(8)));
typedef _Float16 half2_t __attribute__((ext_vector_type(2)));
typedef float f32x4 __attribute__((ext_vector_type(4)));

// ----------------------------------------------------------------------------
// fp32 -> fp16 convert (weights)
// ----------------------------------------------------------------------------
__global__ void cvt_f16(const float* __restrict__ src, _Float16* __restrict__ dst, int n) {
    int i = blockIdx.x * 256 + threadIdx.x;
    if (i < n) dst[i] = (_Float16)src[i];
}

// ----------------------------------------------------------------------------
// Transpose + convert: src fp32 [b][C][PIX] -> dst fp16 [b][PIX][C].  C=256.
// ----------------------------------------------------------------------------
__launch_bounds__(256)
__global__ void transpose_to_f16(const float* __restrict__ src,
                                 _Float16* __restrict__ dst, int C) {
    __shared__ _Float16 tl[64][66];
    const int b  = blockIdx.z;
    const int p0 = blockIdx.x * 64;
    const int c0 = blockIdx.y * 64;
    const int tx = threadIdx.x;
    const int ty = threadIdx.y;
    const float* s = src + (size_t)b * C * PIX;
    _Float16* d = dst + (size_t)b * PIX * C;
#pragma unroll
    for (int cc = ty; cc < 64; cc += 4)
        tl[cc][tx] = (_Float16)s[(size_t)(c0 + cc) * PIX + p0 + tx];
    __syncthreads();
#pragma unroll
    for (int pp = ty; pp < 64; pp += 4)
        d[(size_t)(p0 + pp) * C + c0 + tx] = tl[tx][pp];
}

// ----------------------------------------------------------------------------
// fp16 MFMA GEMM: Y[b][m][n] = sum_k A[m][k] * BT[b][n][k] + bias[m]
// PAIR=true: output stored pair-interleaved [m/2][n][2] (channel pairs packed
// into one dword per pixel) for the attention kernel's packed-fp16 reads.
// D-frag rows (lane quad q holds rows 4q..4q+3) keep both pair members
// in-lane, so the packed store stays dword-coalesced across lanes.
// ----------------------------------------------------------------------------
template <typename OutT, bool PAIR>
__launch_bounds__(256)
__global__ void gemm16(const _Float16* __restrict__ A,
                       const _Float16* __restrict__ BT,
                       const float* __restrict__ bias,
                       OutT* __restrict__ Y,
                       int M, int K, int N) {
    __shared__ _Float16 Asl[128][40];
    __shared__ _Float16 Bsl[128][40];
    const int b = blockIdx.z;
    const _Float16* Bb = BT + (size_t)b * N * K;
    OutT* Yb = Y + (size_t)b * M * N;
    const int m0 = blockIdx.y * 128;
    const int n0 = blockIdx.x * 128;
    const int t    = threadIdx.x;
    const int lane = t & 63;
    const int w    = t >> 6;
    const int wm = w >> 1, wn = w & 1;
    const int l15 = lane & 15;
    const int kq  = (lane >> 4) * 8;

    f32x4 acc[4][4];
#pragma unroll
    for (int mt = 0; mt < 4; mt++)
#pragma unroll
        for (int nt = 0; nt < 4; nt++)
            acc[mt][nt] = (f32x4){0.f, 0.f, 0.f, 0.f};

    for (int k0 = 0; k0 < K; k0 += 32) {
        __syncthreads();
#pragma unroll
        for (int i = 0; i < 2; i++) {
            int idx = t + i * 256;
            int row = idx >> 2;
            int seg = (idx & 3) * 8;
            *(half8_t*)&Asl[row][seg] = *(const half8_t*)(A  + (size_t)(m0 + row) * K + k0 + seg);
            *(half8_t*)&Bsl[row][seg] = *(const half8_t*)(Bb + (size_t)(n0 + row) * K + k0 + seg);
        }
        __syncthreads();
        half8_t af[4], bf[4];
#pragma unroll
        for (int mt = 0; mt < 4; mt++)
            af[mt] = *(const half8_t*)&Asl[wm * 64 + mt * 16 + l15][kq];
#pragma unroll
        for (int nt = 0; nt < 4; nt++)
            bf[nt] = *(const half8_t*)&Bsl[wn * 64 + nt * 16 + l15][kq];
#pragma unroll
        for (int mt = 0; mt < 4; mt++)
#pragma unroll
            for (int nt = 0; nt < 4; nt++)
                acc[mt][nt] = __builtin_amdgcn_mfma_f32_16x16x32_f16(
                    af[mt], bf[nt], acc[mt][nt], 0, 0, 0);
    }

    const int rq = lane >> 4;
    if constexpr (PAIR) {
        unsigned* Yp = (unsigned*)Yb;   // (M/2) x N dwords
#pragma unroll
        for (int mt = 0; mt < 4; mt++) {
#pragma unroll
            for (int s = 0; s < 2; s++) {
                int mp = m0 + wm * 64 + mt * 16 + rq * 4 + 2 * s;
                float b0 = bias[mp], b1 = bias[mp + 1];
#pragma unroll
                for (int nt = 0; nt < 4; nt++) {
                    int col = n0 + wn * 64 + nt * 16 + l15;
                    half2_t hv;
                    hv.x = (_Float16)(acc[mt][nt][2 * s]     + b0);
                    hv.y = (_Float16)(acc[mt][nt][2 * s + 1] + b1);
                    Yp[(size_t)(mp >> 1) * N + col] = __builtin_bit_cast(unsigned, hv);
                }
            }
        }
    } else {
#pragma unroll
        for (int mt = 0; mt < 4; mt++) {
#pragma unroll
            for (int r = 0; r < 4; r++) {
                int m = m0 + wm * 64 + mt * 16 + rq * 4 + r;
                float bs = bias[m];
                OutT* yp = Yb + (size_t)m * N + n0 + wn * 64;
#pragma unroll
                for (int nt = 0; nt < 4; nt++)
                    yp[nt * 16 + l15] = (OutT)(acc[mt][nt][r] + bs);
            }
        }
    }
}

// ----------------------------------------------------------------------------
// Shfl attention v3 on pair-interleaved fp16 qkv.
// One wave = one (b, h, y) row. Per key-row: 32 coalesced dword loads
// (16 k-pairs + 16 v-pairs); per neighbor offset: 16 packed shfls + 16
// fdot2 for QK, 16 packed shfls + 32 mixed FMA for PV.
// Zero-padding: OOB neighbors add exp(rpb) to denom, v=0.
// ----------------------------------------------------------------------------
template <int KS, int DIL>
__device__ __forceinline__ void attn_wave(const unsigned* __restrict__ base,  // batch base, dwords
                                          const float* __restrict__ rp,
                                          float* __restrict__ outp,           // + (b*CDIM+h*HD)*PIX + y*64
                                          int h, int y) {
    const int x = threadIdx.x;   // 0..63

    const unsigned* qb = base + (size_t)(h * 16) * PIX + y * W_IMG + x;
    const unsigned* kb = base + (size_t)(128 + h * 16) * PIX + x;
    const unsigned* vb = base + (size_t)(256 + h * 16) * PIX + x;

    half2_t qh[16];
#pragma unroll
    for (int d2 = 0; d2 < 16; d2++)
        qh[d2] = __builtin_bit_cast(half2_t, qb[(size_t)d2 * PIX]);

    float acc[HD];
#pragma unroll
    for (int d = 0; d < HD; d++) acc[d] = 0.f;
    float denom = 0.f;

#pragma unroll 1
    for (int i = 0; i < KS; i++) {
        const int yy = y + (i - KS / 2) * DIL;
        const float* rrow = rp + i * KS;
        if ((unsigned)yy < (unsigned)H_IMG) {
            int kr[16], vr[16];
            const unsigned* ko = kb + yy * W_IMG;
            const unsigned* vo = vb + yy * W_IMG;
#pragma unroll
            for (int d2 = 0; d2 < 16; d2++) {
                kr[d2] = (int)ko[(size_t)d2 * PIX];
                vr[d2] = (int)vo[(size_t)d2 * PIX];
            }
#pragma unroll
            for (int j = 0; j < KS; j++) {
                const int xx = x + (j - KS / 2) * DIL;
                const int src = xx & 63;
                const bool vx = (unsigned)xx < (unsigned)W_IMG;
                float s = 0.f;
#pragma unroll
                for (int d2 = 0; d2 < 16; d2++) {
                    half2_t kk = __builtin_bit_cast(half2_t, __shfl(kr[d2], src));
#if __has_builtin(__builtin_amdgcn_fdot2)
                    s = __builtin_amdgcn_fdot2(qh[d2], kk, s, false);
#else
                    s += (float)qh[d2].x * (float)kk.x + (float)qh[d2].y * (float)kk.y;
#endif
                }
                const float rb = rrow[j];
                float logit = fmaf(s, ATT_SCALE, rb);
                logit = vx ? logit : rb;
                const float wgt = __expf(logit);
                denom += wgt;
                const float wv = vx ? wgt : 0.f;
#pragma unroll
                for (int d2 = 0; d2 < 16; d2++) {
                    half2_t vv = __builtin_bit_cast(half2_t, __shfl(vr[d2], src));
                    acc[2 * d2]     += wv * (float)vv.x;
                    acc[2 * d2 + 1] += wv * (float)vv.y;
                }
            }
        } else {
#pragma unroll
            for (int j = 0; j < KS; j++) denom += __expf(rrow[j]);
        }
    }

    const float inv = 1.f / denom;
#pragma unroll
    for (int d = 0; d < HD; d++) outp[(size_t)d * PIX] = acc[d] * inv;
}

__launch_bounds__(256)
__global__ void attn_v3(const unsigned* __restrict__ qkv,   // pair dwords [b][384][PIX]
                        const float* __restrict__ rpb0,
                        const float* __restrict__ rpb1,
                        const float* __restrict__ rpb2,
                        float* __restrict__ out) {
    const int b  = blockIdx.x >> 1;
    const int hh = blockIdx.x & 1;
    const int y  = blockIdx.y;
    const int ty = threadIdx.y;
    // balanced head groups: {0,1,2,7}=3*25+81=156 visits, {3,4,5,6}=25+3*49=172
    const int h = hh ? (3 + ty) : ((ty == 3) ? 7 : ty);

    const unsigned* base = qkv + (size_t)b * (QKV_C / 2) * PIX;
    float* outp = out + ((size_t)b * CDIM + h * HD) * PIX + y * W_IMG + threadIdx.x;

    if (h < 4) {
        attn_wave<5, 1>(base, rpb0 + h * 25, outp, h, y);
    } else if (h < 7) {
        attn_wave<7, 2>(base, rpb1 + (h - 4) * 49, outp, h, y);
    } else {
        attn_wave<9, 3>(base, rpb2, outp, h, y);
    }
}

// ----------------------------------------------------------------------------
extern "C" void kernel_launch(void* const* d_in, const int* in_sizes, int n_in,
                              void* d_out, int out_size, void* d_ws, size_t ws_size,
                              hipStream_t stream) {
    const float* x      = (const float*)d_in[0];
    const float* qkv_w  = (const float*)d_in[1];
    const float* qkv_b  = (const float*)d_in[2];
    const float* proj_w = (const float*)d_in[3];
    const float* proj_b = (const float*)d_in[4];
    const float* rpb0   = (const float*)d_in[5];
    const float* rpb1   = (const float*)d_in[6];
    const float* rpb2   = (const float*)d_in[7];
    float* out = (float*)d_out;

    // Workspace: qkv16 24 MB | att32 16 MB | T16 8 MB | W16+P16 0.5 MB
    char* ws = (char*)d_ws;
    _Float16* qkv16 = (_Float16*)ws;
    float*    att32 = (float*)(ws + (size_t)NB * QKV_C * PIX * 2);
    _Float16* T16   = (_Float16*)(ws + (size_t)NB * QKV_C * PIX * 2 + (size_t)NB * CDIM * PIX * 4);
    _Float16* W16   = T16 + (size_t)NB * PIX * CDIM;
    _Float16* P16   = W16 + (size_t)QKV_C * CDIM;

    cvt_f16<<<dim3((QKV_C * CDIM + 255) / 256), dim3(256), 0, stream>>>(qkv_w, W16, QKV_C * CDIM);
    cvt_f16<<<dim3((CDIM * CDIM + 255) / 256), dim3(256), 0, stream>>>(proj_w, P16, CDIM * CDIM);

    transpose_to_f16<<<dim3(PIX / 64, CDIM / 64, NB), dim3(64, 4), 0, stream>>>(x, T16, CDIM);

    // QKV GEMM, pair-interleaved fp16 output
    gemm16<_Float16, true><<<dim3(PIX / 128, QKV_C / 128, NB), dim3(256), 0, stream>>>(
        W16, T16, qkv_b, qkv16, QKV_C, CDIM, PIX);

    // Fused multi-range shfl attention v3: 512 blocks x 4 waves, balanced heads
    attn_v3<<<dim3(NB * 2, H_IMG), dim3(64, 4), 0, stream>>>(
        (const unsigned*)qkv16, rpb0, rpb1, rpb2, att32);

    transpose_to_f16<<<dim3(PIX / 64, CDIM / 64, NB), dim3(64, 4), 0, stream>>>(att32, T16, CDIM);

    // Proj GEMM, fp32 row-major output
    gemm16<float, false><<<dim3(PIX / 128, CDIM / 128, NB), dim3(256), 0, stream>>>(
        P16, T16, proj_b, out, CDIM, CDIM, PIX);
}